// Round 4
// baseline (443.076 us; speedup 1.0000x reference)
//
#include <hip/hip_runtime.h>

typedef unsigned short ushort;
typedef unsigned int uint;
typedef __bf16 bf16x8 __attribute__((ext_vector_type(8)));
typedef float floatx4 __attribute__((ext_vector_type(4)));
typedef ushort ushort8 __attribute__((ext_vector_type(8)));

constexpr int LQ = 5440;
constexpr int ROWS = 43520;   // batch(8) * 5440

__device__ __forceinline__ ushort f2b(float f) {
  union { float f; uint i; } v; v.f = f;
  uint r = v.i + 0x7FFFu + ((v.i >> 16) & 1u);
  return (ushort)(r >> 16);
}
__device__ __forceinline__ float blo(uint u) {
  union { uint i; float f; } v; v.i = u << 16; return v.f;
}
__device__ __forceinline__ float bhi(uint u) {
  union { uint i; float f; } v; v.i = u & 0xFFFF0000u; return v.f;
}

// ---------------- precast: query -> qb, inpf -> ib (fp32 -> bf16) ----------------
__global__ __launch_bounds__(256) void precast_kernel(
    const float* __restrict__ q, const float* __restrict__ x,
    ushort* __restrict__ qb, ushort* __restrict__ ib) {
  int bx = blockIdx.x;
  const float* src; ushort* dst;
  if (bx < 5440) { src = q; dst = qb; } else { src = x; dst = ib; bx -= 5440; }
  size_t i = ((size_t)bx * 256 + threadIdx.x) * 8;
  float4 a = *(const float4*)(src + i);
  float4 b = *(const float4*)(src + i + 4);
  ushort8 o;
  o[0] = f2b(a.x); o[1] = f2b(a.y); o[2] = f2b(a.z); o[3] = f2b(a.w);
  o[4] = f2b(b.x); o[5] = f2b(b.y); o[6] = f2b(b.z); o[7] = f2b(b.w);
  *(ushort8*)(dst + i) = o;
}

// ---------------- weight transpose + cast: Wt[n][k] bf16 ----------------
__global__ __launch_bounds__(256) void wcast_kernel(
    const float* __restrict__ Wv, const float* __restrict__ Wo,
    const float* __restrict__ Wa, const float* __restrict__ Wu,
    ushort* __restrict__ Wt) {
  int k = threadIdx.x;    // 0..255
  int n = blockIdx.x;     // 0..255
  int m = blockIdx.y;     // 0..3
  const float* src = (m == 0) ? Wv : (m == 1) ? Wo : (m == 2) ? Wa : Wu;
  int N = (m == 2) ? 128 : 256;
  if (n >= N) return;
  size_t off = (size_t)m * 65536 - ((m == 3) ? 32768 : 0);  // 0,65536,131072,163840
  Wt[off + (size_t)n * 256 + k] = f2b(src[(size_t)k * N + n]);
}

// ---------------- MFMA 128x128 tile mainloop (K=256, BK=32), bf16 A ----------------
// A-frag: A[m=lane&15][k=quad*8+j]; B-frag: B[k=quad*8+j][n=lane&15]
// C/D:    col=lane&15, row=quad*4+reg
__device__ __forceinline__ void mfma_tile128(
    const ushort* __restrict__ Ab, const ushort* __restrict__ Bt,
    int row_base, int n0, ushort* At, ushort* Bs, floatx4 (&acc)[4][4]) {
  const int t = threadIdx.x;
  const int r = t >> 1, half = t & 1;
  const int lane = t & 63, wv = t >> 6;
  const int quad = lane >> 4, l15 = lane & 15;
  const int m0w = (wv >> 1) * 64, n0w = (wv & 1) * 64;
#pragma unroll
  for (int i = 0; i < 4; ++i)
#pragma unroll
    for (int j = 0; j < 4; ++j) acc[i][j] = floatx4{0.f, 0.f, 0.f, 0.f};

  for (int k0 = 0; k0 < 256; k0 += 32) {
    {
      const ushort* ap = Ab + (size_t)(row_base + r) * 256 + k0 + half * 16;
      *(ushort8*)&At[r * 32 + half * 16]     = *(const ushort8*)ap;
      *(ushort8*)&At[r * 32 + half * 16 + 8] = *(const ushort8*)(ap + 8);
    }
    {
      const ushort* bp = Bt + (size_t)(n0 + r) * 256 + k0 + half * 16;
      *(ushort8*)&Bs[r * 32 + half * 16]     = *(const ushort8*)bp;
      *(ushort8*)&Bs[r * 32 + half * 16 + 8] = *(const ushort8*)(bp + 8);
    }
    __syncthreads();
    bf16x8 af[4], bfv[4];
#pragma unroll
    for (int ti = 0; ti < 4; ++ti)
      af[ti] = *(const bf16x8*)&At[(m0w + ti * 16 + l15) * 32 + quad * 8];
#pragma unroll
    for (int tj = 0; tj < 4; ++tj)
      bfv[tj] = *(const bf16x8*)&Bs[(n0w + tj * 16 + l15) * 32 + quad * 8];
#pragma unroll
    for (int ti = 0; ti < 4; ++ti)
#pragma unroll
      for (int tj = 0; tj < 4; ++tj)
        acc[ti][tj] = __builtin_amdgcn_mfma_f32_16x16x32_bf16(af[ti], bfv[tj], acc[ti][tj], 0, 0, 0);
    __syncthreads();
  }
}

// ---------------- K1: value GEMM -> bf16 value (u32 dim-pairs) ----------------
__global__ __launch_bounds__(256) void gemm_val_kernel(
    const ushort* __restrict__ Xb, const ushort* __restrict__ WtV,
    const float* __restrict__ bval, uint* __restrict__ value32) {
  __shared__ ushort At[4096];
  __shared__ ushort Bs[4096];
  floatx4 acc[4][4];
  int row_base = blockIdx.x * 128, n0 = blockIdx.y * 128;
  mfma_tile128(Xb, WtV, row_base, n0, At, Bs, acc);
  const int t = threadIdx.x, lane = t & 63, wv = t >> 6;
  const int quad = lane >> 4, l15 = lane & 15;
  const int m0w = (wv >> 1) * 64, n0w = (wv & 1) * 64;
#pragma unroll
  for (int tj = 0; tj < 4; ++tj) {
    int gcol = n0 + n0w + tj * 16 + l15;
    float b = bval[gcol];
#pragma unroll
    for (int ti = 0; ti < 4; ++ti)
#pragma unroll
      for (int reg = 0; reg < 4; ++reg) {
        int grow = row_base + m0w + ti * 16 + quad * 4 + reg;
        float val = acc[ti][tj][reg] + b;
        float part = __shfl_xor(val, 1, 64);
        if ((l15 & 1) == 0) {
          uint p = (uint)f2b(val) | ((uint)f2b(part) << 16);
          value32[(size_t)grow * 128 + (gcol >> 1)] = p;
        }
      }
  }
}

// ---------------- K2: offset GEMM -> park pixel x,y (float2) in slot front ----------------
__global__ __launch_bounds__(256) void gemm_off_kernel(
    const ushort* __restrict__ Qb, const ushort* __restrict__ WtO,
    const float* __restrict__ boff, const float* __restrict__ refp,
    float* __restrict__ tblf) {
  __shared__ ushort At[4096];
  __shared__ ushort Bs[4096];
  floatx4 acc[4][4];
  int row_base = blockIdx.x * 128, n0 = blockIdx.y * 128;
  mfma_tile128(Qb, WtO, row_base, n0, At, Bs, acc);
  const int t = threadIdx.x, lane = t & 63, wv = t >> 6;
  const int quad = lane >> 4, l15 = lane & 15;
  const int m0w = (wv >> 1) * 64, n0w = (wv & 1) * 64;
#pragma unroll
  for (int tj = 0; tj < 4; ++tj) {
    int gcol = n0 + n0w + tj * 16 + l15;
    float b = boff[gcol];
    int pair = gcol >> 1, xy = gcol & 1;
    int hh = pair >> 4, lp = pair & 15, l = lp >> 2;
    float lw = (float)(64 >> l);
#pragma unroll
    for (int ti = 0; ti < 4; ++ti)
#pragma unroll
      for (int reg = 0; reg < 4; ++reg) {
        int grow = row_base + m0w + ti * 16 + quad * 4 + reg;
        float ref = refp[(size_t)grow * 8 + l * 2 + xy];
        float pos = ref * lw + (acc[ti][tj][reg] + b) - 0.5f;
        float part = __shfl_xor(pos, 1, 64);
        if ((l15 & 1) == 0) {
          float2 o; o.x = pos; o.y = part;
          *(float2*)(tblf + (((size_t)grow * 8 + hh) * 16 + lp) * 4) = o;
        }
      }
  }
}

// ---------------- K3: attn GEMM (64x128 tile) + LDS softmax + finalize slots ----------------
// slot = {i00|i01<<16, i10|i11<<16, bf16(w00*aw)|bf16(w01*aw)<<16, bf16(w10*aw)|bf16(w11*aw)<<16}
union KU {
  struct { ushort At[2048]; ushort Bs[4096]; } g;
  float ct[64 * 132];
  __device__ KU() {}
};
__global__ __launch_bounds__(256) void gemm_attn_kernel(
    const ushort* __restrict__ Qb, const ushort* __restrict__ WtA,
    const float* __restrict__ battn, uint4* __restrict__ tblq) {
  __shared__ KU u;
  floatx4 acc[8];
  const int t = threadIdx.x;
  const int lane = t & 63, wv = t >> 6;
  const int quad = lane >> 4, l15 = lane & 15;
  int row_base = blockIdx.x * 64;
#pragma unroll
  for (int j = 0; j < 8; ++j) acc[j] = floatx4{0.f, 0.f, 0.f, 0.f};

  for (int k0 = 0; k0 < 256; k0 += 32) {
    {
      int r = t >> 2, seg = t & 3;
      *(ushort8*)&u.g.At[r * 32 + seg * 8] =
          *(const ushort8*)(Qb + (size_t)(row_base + r) * 256 + k0 + seg * 8);
    }
#pragma unroll
    for (int i = 0; i < 2; ++i) {
      int item = t + 256 * i;
      int r = item >> 2, seg = item & 3;
      *(ushort8*)&u.g.Bs[r * 32 + seg * 8] =
          *(const ushort8*)(WtA + (size_t)r * 256 + k0 + seg * 8);
    }
    __syncthreads();
    bf16x8 af = *(const bf16x8*)&u.g.At[(wv * 16 + l15) * 32 + quad * 8];
#pragma unroll
    for (int tj = 0; tj < 8; ++tj) {
      bf16x8 bf = *(const bf16x8*)&u.g.Bs[(tj * 16 + l15) * 32 + quad * 8];
      acc[tj] = __builtin_amdgcn_mfma_f32_16x16x32_bf16(af, bf, acc[tj], 0, 0, 0);
    }
    __syncthreads();
  }
  // dump C (+bias) to LDS transposed store
#pragma unroll
  for (int tj = 0; tj < 8; ++tj) {
    int col = tj * 16 + l15;
    float bb = battn[col];
#pragma unroll
    for (int reg = 0; reg < 4; ++reg) {
      int rr = wv * 16 + quad * 4 + reg;
      u.ct[rr * 132 + col] = acc[tj][reg] + bb;
    }
  }
  __syncthreads();
  // each thread: 2 (row,head) groups; serial softmax + slot finalize
#pragma unroll
  for (int i = 0; i < 2; ++i) {
    int gidx = t + 256 * i;            // 0..511
    int row = gidx >> 3, h = gidx & 7;
    int grow = row_base + row;
    float xv[16];
    *(float4*)&xv[0]  = *(const float4*)&u.ct[row * 132 + h * 16];
    *(float4*)&xv[4]  = *(const float4*)&u.ct[row * 132 + h * 16 + 4];
    *(float4*)&xv[8]  = *(const float4*)&u.ct[row * 132 + h * 16 + 8];
    *(float4*)&xv[12] = *(const float4*)&u.ct[row * 132 + h * 16 + 12];
    float m = xv[0];
#pragma unroll
    for (int j = 1; j < 16; ++j) m = fmaxf(m, xv[j]);
    float ssum = 0.f;
#pragma unroll
    for (int j = 0; j < 16; ++j) { xv[j] = __expf(xv[j] - m); ssum += xv[j]; }
    float inv = 1.f / ssum;
    size_t sbase = ((size_t)grow * 8 + h) * 16;
#pragma unroll
    for (int j = 0; j < 16; ++j) {
      const int l = j >> 2;
      const int wd = 64 >> l;
      const int st = (l == 0) ? 0 : (l == 1) ? 4096 : (l == 2) ? 5120 : 5376;
      uint4* sp = &tblq[sbase + j];
      float2 xy = *(const float2*)sp;
      float aw = xv[j] * inv;
      float fx = floorf(xy.x), fy = floorf(xy.y);
      float lx = xy.x - fx, ly = xy.y - fy;
      int x0 = (int)fx, y0 = (int)fy, x1 = x0 + 1, y1 = y0 + 1;
      int cx0 = min(max(x0, 0), wd - 1), cx1 = min(max(x1, 0), wd - 1);
      int cy0 = min(max(y0, 0), wd - 1), cy1 = min(max(y1, 0), wd - 1);
      float vx0 = (x0 >= 0 && x0 < wd) ? 1.f : 0.f;
      float vx1 = (x1 >= 0 && x1 < wd) ? 1.f : 0.f;
      float vy0 = (y0 >= 0 && y0 < wd) ? 1.f : 0.f;
      float vy1 = (y1 >= 0 && y1 < wd) ? 1.f : 0.f;
      float g00 = (1.f - lx) * (1.f - ly) * vx0 * vy0 * aw;
      float g01 = lx * (1.f - ly) * vx1 * vy0 * aw;
      float g10 = (1.f - lx) * ly * vx0 * vy1 * aw;
      float g11 = lx * ly * vx1 * vy1 * aw;
      uint i00 = st + cy0 * wd + cx0, i01 = st + cy0 * wd + cx1;
      uint i10 = st + cy1 * wd + cx0, i11 = st + cy1 * wd + cx1;
      uint4 ov;
      ov.x = i00 | (i01 << 16);
      ov.y = i10 | (i11 << 16);
      ov.z = (uint)f2b(g00) | ((uint)f2b(g01) << 16);
      ov.w = (uint)f2b(g10) | ((uint)f2b(g11) << 16);
      *sp = ov;
    }
  }
}

// ---------------- K5: bilinear core. wave=(row,h); lane = s(sample-slot)*8 + g(dim-group) ----------------
__global__ __launch_bounds__(512) void core_kernel(
    const uint* __restrict__ value32, const uint* __restrict__ tbl32,
    uint* __restrict__ coreo32) {
  const int bx = blockIdx.x;
  const int b = bx & 7;                       // XCD-affine batch slice
  const int brow = b * LQ + (bx >> 3);
  const int t = threadIdx.x;
  const int h = t >> 6, lane = t & 63;
  const int s = lane >> 3, g = lane & 7;
  const uint v = tbl32[((size_t)brow * 8 + h) * 64 + lane];
  const uint2* vb = (const uint2*)value32 + (size_t)b * (LQ * 64) + h * 8 + g;
  float a0 = 0.f, a1 = 0.f, a2 = 0.f, a3 = 0.f;
#pragma unroll
  for (int lpi = 0; lpi < 2; ++lpi) {
    int base4 = (s + lpi * 8) * 4;
    uint i01 = (uint)__shfl((int)v, base4 + 0, 64);
    uint i23 = (uint)__shfl((int)v, base4 + 1, 64);
    uint wab = (uint)__shfl((int)v, base4 + 2, 64);
    uint wcd = (uint)__shfl((int)v, base4 + 3, 64);
    uint2 v00 = vb[(size_t)(i01 & 0xFFFFu) * 64];
    uint2 v01 = vb[(size_t)(i01 >> 16) * 64];
    uint2 v10 = vb[(size_t)(i23 & 0xFFFFu) * 64];
    uint2 v11 = vb[(size_t)(i23 >> 16) * 64];
    float w00 = blo(wab), w01 = bhi(wab), w10 = blo(wcd), w11 = bhi(wcd);
    a0 = fmaf(w00, blo(v00.x), a0); a1 = fmaf(w00, bhi(v00.x), a1);
    a2 = fmaf(w00, blo(v00.y), a2); a3 = fmaf(w00, bhi(v00.y), a3);
    a0 = fmaf(w01, blo(v01.x), a0); a1 = fmaf(w01, bhi(v01.x), a1);
    a2 = fmaf(w01, blo(v01.y), a2); a3 = fmaf(w01, bhi(v01.y), a3);
    a0 = fmaf(w10, blo(v10.x), a0); a1 = fmaf(w10, bhi(v10.x), a1);
    a2 = fmaf(w10, blo(v10.y), a2); a3 = fmaf(w10, bhi(v10.y), a3);
    a0 = fmaf(w11, blo(v11.x), a0); a1 = fmaf(w11, bhi(v11.x), a1);
    a2 = fmaf(w11, blo(v11.y), a2); a3 = fmaf(w11, bhi(v11.y), a3);
  }
#pragma unroll
  for (int m = 8; m <= 32; m <<= 1) {
    a0 += __shfl_xor(a0, m, 64);
    a1 += __shfl_xor(a1, m, 64);
    a2 += __shfl_xor(a2, m, 64);
    a3 += __shfl_xor(a3, m, 64);
  }
  if (s == 0) {
    uint2 o;
    o.x = (uint)f2b(a0) | ((uint)f2b(a1) << 16);
    o.y = (uint)f2b(a2) | ((uint)f2b(a3) << 16);
    *(uint2*)(coreo32 + (size_t)brow * 128 + h * 16 + g * 2) = o;
  }
}

// ---------------- K4: out GEMM (A = core bf16) -> fp32 d_out ----------------
__global__ __launch_bounds__(256) void gemm_out_kernel(
    const ushort* __restrict__ C, const ushort* __restrict__ WtU,
    const float* __restrict__ bout, float* __restrict__ out) {
  __shared__ ushort At[4096];
  __shared__ ushort Bs[4096];
  floatx4 acc[4][4];
  int row_base = blockIdx.x * 128, n0 = blockIdx.y * 128;
  mfma_tile128(C, WtU, row_base, n0, At, Bs, acc);
  const int t = threadIdx.x, lane = t & 63, wv = t >> 6;
  const int quad = lane >> 4, l15 = lane & 15;
  const int m0w = (wv >> 1) * 64, n0w = (wv & 1) * 64;
#pragma unroll
  for (int tj = 0; tj < 4; ++tj) {
    int gcol = n0 + n0w + tj * 16 + l15;
    float b = bout[gcol];
#pragma unroll
    for (int ti = 0; ti < 4; ++ti)
#pragma unroll
      for (int reg = 0; reg < 4; ++reg) {
        int grow = row_base + m0w + ti * 16 + quad * 4 + reg;
        out[(size_t)grow * 256 + gcol] = acc[ti][tj][reg] + b;
      }
  }
}

extern "C" void kernel_launch(void* const* d_in, const int* in_sizes, int n_in,
                              void* d_out, int out_size, void* d_ws, size_t ws_size,
                              hipStream_t stream) {
  const float* query  = (const float*)d_in[0];
  const float* refp   = (const float*)d_in[1];
  const float* inpf   = (const float*)d_in[2];
  const float* W_val  = (const float*)d_in[5];
  const float* b_val  = (const float*)d_in[6];
  const float* W_off  = (const float*)d_in[7];
  const float* b_off  = (const float*)d_in[8];
  const float* W_attn = (const float*)d_in[9];
  const float* b_attn = (const float*)d_in[10];
  const float* W_out  = (const float*)d_in[11];
  const float* b_out  = (const float*)d_in[12];

  char* ws = (char*)d_ws;
  ushort* Wt    = (ushort*)ws;                        // 458,752 B used (1 MB reserved)
  ushort* qb    = (ushort*)(ws + 1048576);            // 22,282,240 B (query bf16)
  uint*   value = (uint*)(ws + 23330816);             // 22,282,240 B (value bf16 pairs)
  uint*   tbl   = (uint*)(ws + 45613056);             // 89,128,960 B (16B slots)
  ushort* ib    = (ushort*)(ws + 45613056);           // alias tbl head: inpf bf16 (dead before K2)
  uint*   coreo = (uint*)(ws + 1048576);              // alias qb (dead after K3)
  // peak = 134,742,016 B (same as round 3)

  dim3 blk(256);
  precast_kernel  <<<dim3(10880), blk, 0, stream>>>(query, inpf, qb, ib);
  wcast_kernel    <<<dim3(256, 4), blk, 0, stream>>>(W_val, W_off, W_attn, W_out, Wt);
  gemm_val_kernel <<<dim3(340, 2), blk, 0, stream>>>(ib, Wt, b_val, value);
  gemm_off_kernel <<<dim3(340, 2), blk, 0, stream>>>(qb, Wt + 65536, b_off, refp, (float*)tbl);
  gemm_attn_kernel<<<dim3(680), blk, 0, stream>>>(qb, Wt + 131072, b_attn, (uint4*)tbl);
  core_kernel     <<<dim3(ROWS), dim3(512), 0, stream>>>(value, tbl, coreo);
  gemm_out_kernel <<<dim3(340, 2), blk, 0, stream>>>((const ushort*)coreo, Wt + 163840, b_out, (float*)d_out);
}

// Round 5
// 340.240 us; speedup vs baseline: 1.3022x; 1.3022x over previous
//
#include <hip/hip_runtime.h>

typedef unsigned short ushort;
typedef unsigned int uint;
typedef __bf16 bf16x8 __attribute__((ext_vector_type(8)));
typedef float floatx4 __attribute__((ext_vector_type(4)));
typedef ushort ushort8 __attribute__((ext_vector_type(8)));

constexpr int LQ = 5440;
constexpr int ROWS = 43520;   // batch(8) * 5440

__device__ __forceinline__ ushort f2b(float f) {
  union { float f; uint i; } v; v.f = f;
  uint r = v.i + 0x7FFFu + ((v.i >> 16) & 1u);
  return (ushort)(r >> 16);
}
__device__ __forceinline__ float blo(uint u) {
  union { uint i; float f; } v; v.i = u << 16; return v.f;
}
__device__ __forceinline__ float bhi(uint u) {
  union { uint i; float f; } v; v.i = u & 0xFFFF0000u; return v.f;
}

// ---------------- weight transpose + cast: Wt[n][k] bf16 ----------------
// layout: [0]=Wval(256r) [65536]=Woff(256r)+Wattn(128r fused 384-row block) [163840]=Wout(256r)
__global__ __launch_bounds__(256) void wcast_kernel(
    const float* __restrict__ Wv, const float* __restrict__ Wo,
    const float* __restrict__ Wa, const float* __restrict__ Wu,
    ushort* __restrict__ Wt) {
  int k = threadIdx.x;    // 0..255
  int n = blockIdx.x;     // 0..255
  int m = blockIdx.y;     // 0..3
  const float* src = (m == 0) ? Wv : (m == 1) ? Wo : (m == 2) ? Wa : Wu;
  int N = (m == 2) ? 128 : 256;
  if (n >= N) return;
  size_t off = (size_t)m * 65536 - ((m == 3) ? 32768 : 0);  // 0,65536,131072,163840
  Wt[off + (size_t)n * 256 + k] = f2b(src[(size_t)k * N + n]);
}

// ---------------- MFMA 128x128 mainloop, MFMA-order LDS (conflict-free) ----------------
// LDS slot for (tile, lane) at (tile*64+lane)*8 ushorts; lane=(quad,l15) holds
// A[m=tile*16+l15][k=quad*8..+7] (A-frag) / B[k=quad*8..+7][n=tile*16+l15] (B-frag).
template<bool F2B>
__device__ __forceinline__ void mfma_tile128(
    const void* __restrict__ Av, const ushort* __restrict__ Bt,
    int row_base, int n0, ushort* At, ushort* Bs, floatx4 (&acc)[4][4]) {
  const int t = threadIdx.x;
  const int lane = t & 63, wv = t >> 6;
  const int quad = lane >> 4, l15 = lane & 15;
  const int mt0 = (wv >> 1) * 4, nt0 = (wv & 1) * 4;
#pragma unroll
  for (int i = 0; i < 4; ++i)
#pragma unroll
    for (int j = 0; j < 4; ++j) acc[i][j] = floatx4{0.f, 0.f, 0.f, 0.f};

  for (int k0 = 0; k0 < 256; k0 += 32) {
#pragma unroll
    for (int i = 0; i < 2; ++i) {
      int item = t + 256 * i;          // 512 A-chunks: (row r, quad q)
      int r = item >> 2, q = item & 3;
      int slot = ((r >> 4) * 64 + q * 16 + (r & 15)) * 8;
      if (F2B) {
        const float* ap = (const float*)Av + (size_t)(row_base + r) * 256 + k0 + q * 8;
        float4 a0 = *(const float4*)ap, a1 = *(const float4*)(ap + 4);
        ushort8 u;
        u[0] = f2b(a0.x); u[1] = f2b(a0.y); u[2] = f2b(a0.z); u[3] = f2b(a0.w);
        u[4] = f2b(a1.x); u[5] = f2b(a1.y); u[6] = f2b(a1.z); u[7] = f2b(a1.w);
        *(ushort8*)&At[slot] = u;
      } else {
        const ushort* ap = (const ushort*)Av + (size_t)(row_base + r) * 256 + k0 + q * 8;
        *(ushort8*)&At[slot] = *(const ushort8*)ap;
      }
    }
#pragma unroll
    for (int i = 0; i < 2; ++i) {
      int item = t + 256 * i;          // 512 B-chunks: (n-row nr, quad q)
      int nr = item >> 2, q = item & 3;
      int slot = ((nr >> 4) * 64 + q * 16 + (nr & 15)) * 8;
      *(ushort8*)&Bs[slot] = *(const ushort8*)(Bt + (size_t)(n0 + nr) * 256 + k0 + q * 8);
    }
    __syncthreads();
    bf16x8 af[4], bfv[4];
#pragma unroll
    for (int ti = 0; ti < 4; ++ti)
      af[ti] = *(const bf16x8*)&At[((mt0 + ti) * 64 + lane) * 8];
#pragma unroll
    for (int tj = 0; tj < 4; ++tj)
      bfv[tj] = *(const bf16x8*)&Bs[((nt0 + tj) * 64 + lane) * 8];
#pragma unroll
    for (int ti = 0; ti < 4; ++ti)
#pragma unroll
      for (int tj = 0; tj < 4; ++tj)
        acc[ti][tj] = __builtin_amdgcn_mfma_f32_16x16x32_bf16(af[ti], bfv[tj], acc[ti][tj], 0, 0, 0);
    __syncthreads();
  }
}

// ---------------- K1: value GEMM (fp32 A, f2b in staging) -> bf16 value ----------------
__global__ __launch_bounds__(256) void gemm_val_kernel(
    const float* __restrict__ X, const ushort* __restrict__ WtV,
    const float* __restrict__ bval, ushort* __restrict__ value16) {
  __shared__ ushort At[8192];
  __shared__ ushort Bs[8192];
  floatx4 acc[4][4];
  int row_base = blockIdx.x * 128, n0 = blockIdx.y * 128;
  mfma_tile128<true>(X, WtV, row_base, n0, At, Bs, acc);
  const int t = threadIdx.x, lane = t & 63, wv = t >> 6;
  const int quad = lane >> 4, l15 = lane & 15;
  const int mt0 = (wv >> 1) * 4, nt0 = (wv & 1) * 4;
#pragma unroll
  for (int tj = 0; tj < 4; ++tj) {
    int gcol = n0 + (nt0 + tj) * 16 + l15;
    float b = bval[gcol];
#pragma unroll
    for (int ti = 0; ti < 4; ++ti)
#pragma unroll
      for (int reg = 0; reg < 4; ++reg) {
        int grow = row_base + (mt0 + ti) * 16 + quad * 4 + reg;
        value16[(size_t)grow * 256 + gcol] = f2b(acc[ti][tj][reg] + b);
      }
  }
}

// ---------------- K2: fused off+attn GEMM (N=384) + softmax + slot finalize ----------------
// Block 256 thr / 4 waves, 64-row tile. Wave wv owns heads {2wv, 2wv+1}:
// off n-tiles 4wv..4wv+3 (cols 64wv..64wv+63), attn n-tiles 16+2wv,17+2wv.
// slot = {i00|i01<<16, i10|i11<<16, bf16(w00*aw)|bf16(w01*aw)<<16, bf16(w10*aw)|bf16(w11*aw)<<16}
__global__ __launch_bounds__(256) void gemm_oa_kernel(
    const float* __restrict__ Q, const ushort* __restrict__ WtOA,
    const float* __restrict__ boff, const float* __restrict__ battn,
    const float* __restrict__ refp, uint4* __restrict__ tblq) {
  __shared__ ushort At[2048];     // 4 m-tiles  * 64 lanes * 8
  __shared__ ushort Bs[12288];    // 24 n-tiles * 64 lanes * 8
  const int t = threadIdx.x;
  const int lane = t & 63, wv = t >> 6;
  const int quad = lane >> 4, l15 = lane & 15;
  int row_base = blockIdx.x * 64;
  floatx4 accO[4][4];   // [p][ti], n-tile 4wv+p
  floatx4 accA[2][4];   // [q][ti], n-tile 16+2wv+q
#pragma unroll
  for (int p = 0; p < 4; ++p)
#pragma unroll
    for (int ti = 0; ti < 4; ++ti) accO[p][ti] = floatx4{0.f, 0.f, 0.f, 0.f};
#pragma unroll
  for (int q = 0; q < 2; ++q)
#pragma unroll
    for (int ti = 0; ti < 4; ++ti) accA[q][ti] = floatx4{0.f, 0.f, 0.f, 0.f};

  for (int k0 = 0; k0 < 256; k0 += 32) {
    {
      int r = t >> 2, q = t & 3;        // 256 A-chunks
      const float* ap = Q + (size_t)(row_base + r) * 256 + k0 + q * 8;
      float4 a0 = *(const float4*)ap, a1 = *(const float4*)(ap + 4);
      ushort8 u;
      u[0] = f2b(a0.x); u[1] = f2b(a0.y); u[2] = f2b(a0.z); u[3] = f2b(a0.w);
      u[4] = f2b(a1.x); u[5] = f2b(a1.y); u[6] = f2b(a1.z); u[7] = f2b(a1.w);
      *(ushort8*)&At[((r >> 4) * 64 + q * 16 + (r & 15)) * 8] = u;
    }
#pragma unroll
    for (int i = 0; i < 6; ++i) {
      int item = t + 256 * i;           // 1536 B-chunks
      int nr = item >> 2, q = item & 3;
      *(ushort8*)&Bs[((nr >> 4) * 64 + q * 16 + (nr & 15)) * 8] =
          *(const ushort8*)(WtOA + (size_t)nr * 256 + k0 + q * 8);
    }
    __syncthreads();
    bf16x8 af[4];
#pragma unroll
    for (int ti = 0; ti < 4; ++ti)
      af[ti] = *(const bf16x8*)&At[(ti * 64 + lane) * 8];
#pragma unroll
    for (int p = 0; p < 4; ++p) {
      bf16x8 bf = *(const bf16x8*)&Bs[(((4 * wv + p)) * 64 + lane) * 8];
#pragma unroll
      for (int ti = 0; ti < 4; ++ti)
        accO[p][ti] = __builtin_amdgcn_mfma_f32_16x16x32_bf16(af[ti], bf, accO[p][ti], 0, 0, 0);
    }
#pragma unroll
    for (int q = 0; q < 2; ++q) {
      bf16x8 bf = *(const bf16x8*)&Bs[((16 + 2 * wv + q) * 64 + lane) * 8];
#pragma unroll
      for (int ti = 0; ti < 4; ++ti)
        accA[q][ti] = __builtin_amdgcn_mfma_f32_16x16x32_bf16(af[ti], bf, accA[q][ti], 0, 0, 0);
    }
    __syncthreads();
  }

  // epilogue: in-wave softmax + slot finalize
  float boO[4], boA[2];
#pragma unroll
  for (int p = 0; p < 4; ++p) boO[p] = boff[(4 * wv + p) * 16 + l15];
#pragma unroll
  for (int q = 0; q < 2; ++q) boA[q] = battn[(2 * wv + q) * 16 + l15];
  const int lp = l15, l = lp >> 2;
  const int wd = 64 >> l;
  const int st = (l == 0) ? 0 : (l == 1) ? 4096 : (l == 2) ? 5120 : 5376;
  const float lw = (float)wd;
  const int src = (quad << 4) | (2 * (lp & 7));

#pragma unroll
  for (int ti = 0; ti < 4; ++ti)
#pragma unroll
    for (int reg = 0; reg < 4; ++reg) {
      int grow = row_base + ti * 16 + quad * 4 + reg;
      float rx = refp[(size_t)grow * 8 + l * 2];
      float ry = refp[(size_t)grow * 8 + l * 2 + 1];
#pragma unroll
      for (int hh = 0; hh < 2; ++hh) {
        int h = 2 * wv + hh;
        // softmax over the 16 attn cols of (grow, h) -- lanes of this quad
        float xa = accA[hh][ti][reg] + boA[hh];
        float m = xa;
        m = fmaxf(m, __shfl_xor(m, 1, 64));
        m = fmaxf(m, __shfl_xor(m, 2, 64));
        m = fmaxf(m, __shfl_xor(m, 4, 64));
        m = fmaxf(m, __shfl_xor(m, 8, 64));
        float e = __expf(xa - m);
        float ssum = e;
        ssum += __shfl_xor(ssum, 1, 64);
        ssum += __shfl_xor(ssum, 2, 64);
        ssum += __shfl_xor(ssum, 4, 64);
        ssum += __shfl_xor(ssum, 8, 64);
        float aw = e / ssum;
        // fetch off x,y for slot lp: cols 2lp,2lp+1 of tiles 2hh (lp<8) / 2hh+1 (lp>=8)
        float v0 = accO[2 * hh][ti][reg] + boO[2 * hh];
        float v1 = accO[2 * hh + 1][ti][reg] + boO[2 * hh + 1];
        float x_lo = __shfl(v0, src, 64),     x_hi = __shfl(v1, src, 64);
        float y_lo = __shfl(v0, src | 1, 64), y_hi = __shfl(v1, src | 1, 64);
        float xo = (lp < 8) ? x_lo : x_hi;
        float yo = (lp < 8) ? y_lo : y_hi;
        float X = rx * lw + xo - 0.5f;     // == (ref + off/W)*W - 0.5
        float Y = ry * lw + yo - 0.5f;
        float fx = floorf(X), fy = floorf(Y);
        float lx = X - fx, ly = Y - fy;
        int x0 = (int)fx, y0 = (int)fy, x1 = x0 + 1, y1 = y0 + 1;
        int cx0 = min(max(x0, 0), wd - 1), cx1 = min(max(x1, 0), wd - 1);
        int cy0 = min(max(y0, 0), wd - 1), cy1 = min(max(y1, 0), wd - 1);
        float vx0 = (x0 >= 0 && x0 < wd) ? 1.f : 0.f;
        float vx1 = (x1 >= 0 && x1 < wd) ? 1.f : 0.f;
        float vy0 = (y0 >= 0 && y0 < wd) ? 1.f : 0.f;
        float vy1 = (y1 >= 0 && y1 < wd) ? 1.f : 0.f;
        float g00 = (1.f - lx) * (1.f - ly) * vx0 * vy0 * aw;
        float g01 = lx * (1.f - ly) * vx1 * vy0 * aw;
        float g10 = (1.f - lx) * ly * vx0 * vy1 * aw;
        float g11 = lx * ly * vx1 * vy1 * aw;
        uint i00 = st + cy0 * wd + cx0, i01 = st + cy0 * wd + cx1;
        uint i10 = st + cy1 * wd + cx0, i11 = st + cy1 * wd + cx1;
        uint4 ov;
        ov.x = i00 | (i01 << 16);
        ov.y = i10 | (i11 << 16);
        ov.z = (uint)f2b(g00) | ((uint)f2b(g01) << 16);
        ov.w = (uint)f2b(g10) | ((uint)f2b(g11) << 16);
        tblq[((size_t)grow * 8 + h) * 16 + lp] = ov;
      }
    }
}

// ---------------- K3: bilinear core. wave=(row,h); lane = s(slot-group)*8 + g(dim-group) ----------------
// No bpermute: each 8-lane dim-group loads its slot uint4 directly (same-address broadcast).
__global__ __launch_bounds__(512) void core_kernel(
    const ushort* __restrict__ value16, const uint4* __restrict__ tblq,
    uint* __restrict__ coreo32) {
  const int bx = blockIdx.x;
  const int b = bx & 7;                       // XCD-affine batch slice
  const int brow = b * LQ + (bx >> 3);
  const int t = threadIdx.x;
  const int h = t >> 6, lane = t & 63;
  const int s = lane >> 3, g = lane & 7;
  const size_t sbase = ((size_t)brow * 8 + h) * 16;
  uint4 sl0 = tblq[sbase + s];
  uint4 sl1 = tblq[sbase + s + 8];
  const uint2* vb = (const uint2*)value16 + (size_t)b * (LQ * 64) + h * 8 + g;
  float a0 = 0.f, a1 = 0.f, a2 = 0.f, a3 = 0.f;
#pragma unroll
  for (int lpi = 0; lpi < 2; ++lpi) {
    uint4 sl = lpi ? sl1 : sl0;
    uint2 v00 = vb[(size_t)(sl.x & 0xFFFFu) * 64];
    uint2 v01 = vb[(size_t)(sl.x >> 16) * 64];
    uint2 v10 = vb[(size_t)(sl.y & 0xFFFFu) * 64];
    uint2 v11 = vb[(size_t)(sl.y >> 16) * 64];
    float w00 = blo(sl.z), w01 = bhi(sl.z), w10 = blo(sl.w), w11 = bhi(sl.w);
    a0 = fmaf(w00, blo(v00.x), a0); a1 = fmaf(w00, bhi(v00.x), a1);
    a2 = fmaf(w00, blo(v00.y), a2); a3 = fmaf(w00, bhi(v00.y), a3);
    a0 = fmaf(w01, blo(v01.x), a0); a1 = fmaf(w01, bhi(v01.x), a1);
    a2 = fmaf(w01, blo(v01.y), a2); a3 = fmaf(w01, bhi(v01.y), a3);
    a0 = fmaf(w10, blo(v10.x), a0); a1 = fmaf(w10, bhi(v10.x), a1);
    a2 = fmaf(w10, blo(v10.y), a2); a3 = fmaf(w10, bhi(v10.y), a3);
    a0 = fmaf(w11, blo(v11.x), a0); a1 = fmaf(w11, bhi(v11.x), a1);
    a2 = fmaf(w11, blo(v11.y), a2); a3 = fmaf(w11, bhi(v11.y), a3);
  }
#pragma unroll
  for (int m = 8; m <= 32; m <<= 1) {
    a0 += __shfl_xor(a0, m, 64);
    a1 += __shfl_xor(a1, m, 64);
    a2 += __shfl_xor(a2, m, 64);
    a3 += __shfl_xor(a3, m, 64);
  }
  if (s == 0) {
    uint2 o;
    o.x = (uint)f2b(a0) | ((uint)f2b(a1) << 16);
    o.y = (uint)f2b(a2) | ((uint)f2b(a3) << 16);
    *(uint2*)(coreo32 + (size_t)brow * 128 + h * 16 + g * 2) = o;
  }
}

// ---------------- K4: out GEMM (A = core bf16) -> fp32 d_out ----------------
__global__ __launch_bounds__(256) void gemm_out_kernel(
    const ushort* __restrict__ C, const ushort* __restrict__ WtU,
    const float* __restrict__ bout, float* __restrict__ out) {
  __shared__ ushort At[8192];
  __shared__ ushort Bs[8192];
  floatx4 acc[4][4];
  int row_base = blockIdx.x * 128, n0 = blockIdx.y * 128;
  mfma_tile128<false>(C, WtU, row_base, n0, At, Bs, acc);
  const int t = threadIdx.x, lane = t & 63, wv = t >> 6;
  const int quad = lane >> 4, l15 = lane & 15;
  const int mt0 = (wv >> 1) * 4, nt0 = (wv & 1) * 4;
#pragma unroll
  for (int tj = 0; tj < 4; ++tj) {
    int gcol = n0 + (nt0 + tj) * 16 + l15;
    float b = bout[gcol];
#pragma unroll
    for (int ti = 0; ti < 4; ++ti)
#pragma unroll
      for (int reg = 0; reg < 4; ++reg) {
        int grow = row_base + (mt0 + ti) * 16 + quad * 4 + reg;
        out[(size_t)grow * 256 + gcol] = acc[ti][tj][reg] + b;
      }
  }
}

extern "C" void kernel_launch(void* const* d_in, const int* in_sizes, int n_in,
                              void* d_out, int out_size, void* d_ws, size_t ws_size,
                              hipStream_t stream) {
  const float* query  = (const float*)d_in[0];
  const float* refp   = (const float*)d_in[1];
  const float* inpf   = (const float*)d_in[2];
  const float* W_val  = (const float*)d_in[5];
  const float* b_val  = (const float*)d_in[6];
  const float* W_off  = (const float*)d_in[7];
  const float* b_off  = (const float*)d_in[8];
  const float* W_attn = (const float*)d_in[9];
  const float* b_attn = (const float*)d_in[10];
  const float* W_out  = (const float*)d_in[11];
  const float* b_out  = (const float*)d_in[12];

  char* ws = (char*)d_ws;
  ushort* Wt    = (ushort*)ws;                        // 458,752 B used (1 MB reserved)
  ushort* value = (ushort*)(ws + 1048576);            // 22,282,240 B (bf16)
  uint4*  tbl   = (uint4*)(ws + 23330816);            // 89,128,960 B (16 B slots)
  ushort* coreo = (ushort*)(ws + 112459776);          // 22,282,240 B (bf16)
  // peak = 134,742,016 B

  dim3 blk(256);
  wcast_kernel   <<<dim3(256, 4), blk, 0, stream>>>(W_val, W_off, W_attn, W_out, Wt);
  gemm_val_kernel<<<dim3(340, 2), blk, 0, stream>>>(inpf, Wt, b_val, value);
  gemm_oa_kernel <<<dim3(680), blk, 0, stream>>>(query, Wt + 65536, b_off, b_attn, refp, tbl);
  core_kernel    <<<dim3(ROWS), dim3(512), 0, stream>>>(value, tbl, (uint*)coreo);
  gemm_out_kernel<<<dim3(340, 2), blk, 0, stream>>>(coreo, Wt + 163840, b_out, (float*)d_out);
}

// Round 6
// 334.664 us; speedup vs baseline: 1.3239x; 1.0167x over previous
//
#include <hip/hip_runtime.h>

typedef unsigned short ushort;
typedef unsigned int uint;
typedef __bf16 bf16x8 __attribute__((ext_vector_type(8)));
typedef float floatx4 __attribute__((ext_vector_type(4)));
typedef ushort ushort8 __attribute__((ext_vector_type(8)));

constexpr int LQ = 5440;
constexpr int ROWS = 43520;   // batch(8) * 5440

__device__ __forceinline__ ushort f2b(float f) {
  union { float f; uint i; } v; v.f = f;
  uint r = v.i + 0x7FFFu + ((v.i >> 16) & 1u);
  return (ushort)(r >> 16);
}
__device__ __forceinline__ float blo(uint u) {
  union { uint i; float f; } v; v.i = u << 16; return v.f;
}
__device__ __forceinline__ float bhi(uint u) {
  union { uint i; float f; } v; v.i = u & 0xFFFF0000u; return v.f;
}

// ---------------- weight transpose + cast: Wt[n][k] bf16 ----------------
// layout: [0]=Wval(256r) [65536]=Woff(256r)+Wattn(128r) fused 384-row block [163840]=Wout(256r)
__global__ __launch_bounds__(256) void wcast_kernel(
    const float* __restrict__ Wv, const float* __restrict__ Wo,
    const float* __restrict__ Wa, const float* __restrict__ Wu,
    ushort* __restrict__ Wt) {
  int k = threadIdx.x;    // 0..255
  int n = blockIdx.x;     // 0..255
  int m = blockIdx.y;     // 0..3
  const float* src = (m == 0) ? Wv : (m == 1) ? Wo : (m == 2) ? Wa : Wu;
  int N = (m == 2) ? 128 : 256;
  if (n >= N) return;
  size_t off = (size_t)m * 65536 - ((m == 3) ? 32768 : 0);  // 0,65536,131072,163840
  Wt[off + (size_t)n * 256 + k] = f2b(src[(size_t)k * N + n]);
}

// ---------------- 64x128 MFMA mainloop (K=256, BK=32), MFMA-order LDS ----------------
// Wave wv owns n-tiles {2wv, 2wv+1}, all 4 m-tiles. acc[ti][tjj].
template<bool F2B>
__device__ __forceinline__ void tile64_mainloop(
    const void* __restrict__ Av, const ushort* __restrict__ Bt,
    int row_base, int n0, ushort* At, ushort* Bs, floatx4 (&acc)[4][2]) {
  const int t = threadIdx.x;
  const int lane = t & 63, wv = t >> 6;
#pragma unroll
  for (int i = 0; i < 4; ++i)
#pragma unroll
    for (int j = 0; j < 2; ++j) acc[i][j] = floatx4{0.f, 0.f, 0.f, 0.f};

  for (int k0 = 0; k0 < 256; k0 += 32) {
    {
      int r = t >> 2, q = t & 3;       // 256 A-chunks, 1/thread
      int slot = ((r >> 4) * 64 + q * 16 + (r & 15)) * 8;
      if (F2B) {
        const float* ap = (const float*)Av + (size_t)(row_base + r) * 256 + k0 + q * 8;
        float4 a0 = *(const float4*)ap, a1 = *(const float4*)(ap + 4);
        ushort8 u;
        u[0] = f2b(a0.x); u[1] = f2b(a0.y); u[2] = f2b(a0.z); u[3] = f2b(a0.w);
        u[4] = f2b(a1.x); u[5] = f2b(a1.y); u[6] = f2b(a1.z); u[7] = f2b(a1.w);
        *(ushort8*)&At[slot] = u;
      } else {
        const ushort* ap = (const ushort*)Av + (size_t)(row_base + r) * 256 + k0 + q * 8;
        *(ushort8*)&At[slot] = *(const ushort8*)ap;
      }
    }
#pragma unroll
    for (int i = 0; i < 2; ++i) {      // 512 B-chunks, 2/thread
      int item = t + 256 * i;
      int nr = item >> 2, q = item & 3;
      int slot = ((nr >> 4) * 64 + q * 16 + (nr & 15)) * 8;
      *(ushort8*)&Bs[slot] = *(const ushort8*)(Bt + (size_t)(n0 + nr) * 256 + k0 + q * 8);
    }
    __syncthreads();
    bf16x8 af[4], bf[2];
#pragma unroll
    for (int ti = 0; ti < 4; ++ti)
      af[ti] = *(const bf16x8*)&At[(ti * 64 + lane) * 8];
#pragma unroll
    for (int tjj = 0; tjj < 2; ++tjj)
      bf[tjj] = *(const bf16x8*)&Bs[((2 * wv + tjj) * 64 + lane) * 8];
#pragma unroll
    for (int ti = 0; ti < 4; ++ti)
#pragma unroll
      for (int tjj = 0; tjj < 2; ++tjj)
        acc[ti][tjj] = __builtin_amdgcn_mfma_f32_16x16x32_bf16(af[ti], bf[tjj], acc[ti][tjj], 0, 0, 0);
    __syncthreads();
  }
}

// ---------------- K1: value GEMM (fp32 A, f2b in staging) -> bf16 value ----------------
__global__ __launch_bounds__(256) void gemm_val64(
    const float* __restrict__ X, const ushort* __restrict__ WtV,
    const float* __restrict__ bval, ushort* __restrict__ value16) {
  __shared__ ushort At[2048];
  __shared__ ushort Bs[4096];
  floatx4 acc[4][2];
  int row_base = blockIdx.x * 64, n0 = blockIdx.y * 128;
  tile64_mainloop<true>(X, WtV, row_base, n0, At, Bs, acc);
  const int t = threadIdx.x, lane = t & 63, wv = t >> 6;
  const int quad = lane >> 4, l15 = lane & 15;
#pragma unroll
  for (int tjj = 0; tjj < 2; ++tjj) {
    int gcol = n0 + (2 * wv + tjj) * 16 + l15;
    float b = bval[gcol];
#pragma unroll
    for (int ti = 0; ti < 4; ++ti)
#pragma unroll
      for (int reg = 0; reg < 4; ++reg) {
        int grow = row_base + ti * 16 + quad * 4 + reg;
        value16[(size_t)grow * 256 + gcol] = f2b(acc[ti][tjj][reg] + b);
      }
  }
}

// ---------------- K2: off+attn GEMM, head-pair sliced + softmax + slot finalize ----------------
// Block = (row_tile, head-pair hp). B-tiles: off {4hp..4hp+3}, attn {2hp,2hp+1}.
// Wave wv owns m-tile wv. slot = {i00|i01<<16, i10|i11<<16, w00|w01, w10|w11} (bf16*aw)
__global__ __launch_bounds__(256) void gemm_oa_kernel(
    const float* __restrict__ Q, const ushort* __restrict__ WtOA,
    const float* __restrict__ boff, const float* __restrict__ battn,
    const float* __restrict__ refp, uint4* __restrict__ tblq) {
  __shared__ ushort At[2048];
  __shared__ ushort Bs[3072];
  const int t = threadIdx.x;
  const int lane = t & 63, wv = t >> 6;
  const int quad = lane >> 4, l15 = lane & 15;
  const int bx = blockIdx.x;
  const int row_base = (bx % 680) * 64;
  const int hp = bx / 680;            // 0..3
  floatx4 accO[4], accA[2];
#pragma unroll
  for (int p = 0; p < 4; ++p) accO[p] = floatx4{0.f, 0.f, 0.f, 0.f};
#pragma unroll
  for (int q = 0; q < 2; ++q) accA[q] = floatx4{0.f, 0.f, 0.f, 0.f};

  for (int k0 = 0; k0 < 256; k0 += 32) {
    {
      int r = t >> 2, q = t & 3;      // 256 A-chunks
      const float* ap = Q + (size_t)(row_base + r) * 256 + k0 + q * 8;
      float4 a0 = *(const float4*)ap, a1 = *(const float4*)(ap + 4);
      ushort8 u;
      u[0] = f2b(a0.x); u[1] = f2b(a0.y); u[2] = f2b(a0.z); u[3] = f2b(a0.w);
      u[4] = f2b(a1.x); u[5] = f2b(a1.y); u[6] = f2b(a1.z); u[7] = f2b(a1.w);
      *(ushort8*)&At[((r >> 4) * 64 + q * 16 + (r & 15)) * 8] = u;
    }
#pragma unroll
    for (int i = 0; i < 2; ++i) {     // 384 B-chunks
      int item = t + 256 * i;
      if (item < 384) {
        int nrl = item >> 2, q = item & 3;
        int grow_ = (nrl < 64) ? (hp * 64 + nrl) : (256 + hp * 32 + (nrl - 64));
        *(ushort8*)&Bs[((nrl >> 4) * 64 + q * 16 + (nrl & 15)) * 8] =
            *(const ushort8*)(WtOA + (size_t)grow_ * 256 + k0 + q * 8);
      }
    }
    __syncthreads();
    bf16x8 af = *(const bf16x8*)&At[(wv * 64 + lane) * 8];
#pragma unroll
    for (int p = 0; p < 4; ++p) {
      bf16x8 bf = *(const bf16x8*)&Bs[(p * 64 + lane) * 8];
      accO[p] = __builtin_amdgcn_mfma_f32_16x16x32_bf16(af, bf, accO[p], 0, 0, 0);
    }
#pragma unroll
    for (int q = 0; q < 2; ++q) {
      bf16x8 bf = *(const bf16x8*)&Bs[((4 + q) * 64 + lane) * 8];
      accA[q] = __builtin_amdgcn_mfma_f32_16x16x32_bf16(af, bf, accA[q], 0, 0, 0);
    }
    __syncthreads();
  }

  // epilogue: per-thread 8 slot-units (4 reg x 2 heads)
  const int lp = l15, l = lp >> 2;
  const int wd = 64 >> l;
  const int st = (l == 0) ? 0 : (l == 1) ? 4096 : (l == 2) ? 5120 : 5376;
  const float lw = (float)wd;
  const int src = (quad << 4) | (2 * (lp & 7));
  float boO[4], boA[2];
#pragma unroll
  for (int p = 0; p < 4; ++p) boO[p] = boff[(4 * hp + p) * 16 + l15];
#pragma unroll
  for (int q = 0; q < 2; ++q) boA[q] = battn[(2 * hp + q) * 16 + l15];

#pragma unroll
  for (int reg = 0; reg < 4; ++reg) {
    int grow = row_base + wv * 16 + quad * 4 + reg;
    float rx = refp[(size_t)grow * 8 + l * 2];
    float ry = refp[(size_t)grow * 8 + l * 2 + 1];
#pragma unroll
    for (int hh = 0; hh < 2; ++hh) {
      int h = 2 * hp + hh;
      float xa = accA[hh][reg] + boA[hh];
      float m = xa;
      m = fmaxf(m, __shfl_xor(m, 1, 64));
      m = fmaxf(m, __shfl_xor(m, 2, 64));
      m = fmaxf(m, __shfl_xor(m, 4, 64));
      m = fmaxf(m, __shfl_xor(m, 8, 64));
      float e = __expf(xa - m);
      float ssum = e;
      ssum += __shfl_xor(ssum, 1, 64);
      ssum += __shfl_xor(ssum, 2, 64);
      ssum += __shfl_xor(ssum, 4, 64);
      ssum += __shfl_xor(ssum, 8, 64);
      float aw = e / ssum;
      float v0 = accO[2 * hh][reg] + boO[2 * hh];
      float v1 = accO[2 * hh + 1][reg] + boO[2 * hh + 1];
      float x_lo = __shfl(v0, src, 64),     x_hi = __shfl(v1, src, 64);
      float y_lo = __shfl(v0, src | 1, 64), y_hi = __shfl(v1, src | 1, 64);
      float xo = (lp < 8) ? x_lo : x_hi;
      float yo = (lp < 8) ? y_lo : y_hi;
      float X = rx * lw + xo - 0.5f;     // == (ref + off/W)*W - 0.5
      float Y = ry * lw + yo - 0.5f;
      float fx = floorf(X), fy = floorf(Y);
      float lx = X - fx, ly = Y - fy;
      int x0 = (int)fx, y0 = (int)fy, x1 = x0 + 1, y1 = y0 + 1;
      int cx0 = min(max(x0, 0), wd - 1), cx1 = min(max(x1, 0), wd - 1);
      int cy0 = min(max(y0, 0), wd - 1), cy1 = min(max(y1, 0), wd - 1);
      float vx0 = (x0 >= 0 && x0 < wd) ? 1.f : 0.f;
      float vx1 = (x1 >= 0 && x1 < wd) ? 1.f : 0.f;
      float vy0 = (y0 >= 0 && y0 < wd) ? 1.f : 0.f;
      float vy1 = (y1 >= 0 && y1 < wd) ? 1.f : 0.f;
      float g00 = (1.f - lx) * (1.f - ly) * vx0 * vy0 * aw;
      float g01 = lx * (1.f - ly) * vx1 * vy0 * aw;
      float g10 = (1.f - lx) * ly * vx0 * vy1 * aw;
      float g11 = lx * ly * vx1 * vy1 * aw;
      uint i00 = st + cy0 * wd + cx0, i01 = st + cy0 * wd + cx1;
      uint i10 = st + cy1 * wd + cx0, i11 = st + cy1 * wd + cx1;
      uint4 ov;
      ov.x = i00 | (i01 << 16);
      ov.y = i10 | (i11 << 16);
      ov.z = (uint)f2b(g00) | ((uint)f2b(g01) << 16);
      ov.w = (uint)f2b(g10) | ((uint)f2b(g11) << 16);
      tblq[((size_t)grow * 8 + h) * 16 + lp] = ov;
    }
  }
}

// ---------------- K3: bilinear core, 2 rows per wave ----------------
__global__ __launch_bounds__(512) void core_kernel(
    const ushort* __restrict__ value16, const uint4* __restrict__ tblq,
    uint* __restrict__ coreo32) {
  const int bx = blockIdx.x;           // 21760
  const int b = bx & 7;                // XCD-affine batch slice
  const int pr = bx >> 3;              // 0..2719
  const int brow0 = b * LQ + pr * 2;
  const int t = threadIdx.x;
  const int h = t >> 6, lane = t & 63;
  const int s = lane >> 3, g = lane & 7;
  const size_t sb = ((size_t)brow0 * 8 + h) * 16;
  uint4 sA0 = tblq[sb + s];
  uint4 sA1 = tblq[sb + 8 + s];
  uint4 sB0 = tblq[sb + 128 + s];
  uint4 sB1 = tblq[sb + 136 + s];
  const uint2* vb = (const uint2*)value16 + (size_t)b * (LQ * 64) + h * 8 + g;
  float a[4] = {0.f, 0.f, 0.f, 0.f};
  float c[4] = {0.f, 0.f, 0.f, 0.f};

  auto proc = [&](const uint4& sl, float* ac) {
    uint2 v00 = vb[(size_t)(sl.x & 0xFFFFu) * 64];
    uint2 v01 = vb[(size_t)(sl.x >> 16) * 64];
    uint2 v10 = vb[(size_t)(sl.y & 0xFFFFu) * 64];
    uint2 v11 = vb[(size_t)(sl.y >> 16) * 64];
    float w00 = blo(sl.z), w01 = bhi(sl.z), w10 = blo(sl.w), w11 = bhi(sl.w);
    ac[0] = fmaf(w00, blo(v00.x), ac[0]); ac[1] = fmaf(w00, bhi(v00.x), ac[1]);
    ac[2] = fmaf(w00, blo(v00.y), ac[2]); ac[3] = fmaf(w00, bhi(v00.y), ac[3]);
    ac[0] = fmaf(w01, blo(v01.x), ac[0]); ac[1] = fmaf(w01, bhi(v01.x), ac[1]);
    ac[2] = fmaf(w01, blo(v01.y), ac[2]); ac[3] = fmaf(w01, bhi(v01.y), ac[3]);
    ac[0] = fmaf(w10, blo(v10.x), ac[0]); ac[1] = fmaf(w10, bhi(v10.x), ac[1]);
    ac[2] = fmaf(w10, blo(v10.y), ac[2]); ac[3] = fmaf(w10, bhi(v10.y), ac[3]);
    ac[0] = fmaf(w11, blo(v11.x), ac[0]); ac[1] = fmaf(w11, bhi(v11.x), ac[1]);
    ac[2] = fmaf(w11, blo(v11.y), ac[2]); ac[3] = fmaf(w11, bhi(v11.y), ac[3]);
  };
  proc(sA0, a); proc(sA1, a);
  proc(sB0, c); proc(sB1, c);

#pragma unroll
  for (int m = 8; m <= 32; m <<= 1) {
#pragma unroll
    for (int i = 0; i < 4; ++i) {
      a[i] += __shfl_xor(a[i], m, 64);
      c[i] += __shfl_xor(c[i], m, 64);
    }
  }
  if (s == 0) {
    uint2 o0, o1;
    o0.x = (uint)f2b(a[0]) | ((uint)f2b(a[1]) << 16);
    o0.y = (uint)f2b(a[2]) | ((uint)f2b(a[3]) << 16);
    o1.x = (uint)f2b(c[0]) | ((uint)f2b(c[1]) << 16);
    o1.y = (uint)f2b(c[2]) | ((uint)f2b(c[3]) << 16);
    *(uint2*)(coreo32 + (size_t)brow0 * 128 + h * 16 + g * 2) = o0;
    *(uint2*)(coreo32 + (size_t)(brow0 + 1) * 128 + h * 16 + g * 2) = o1;
  }
}

// ---------------- K4: out GEMM (A = core bf16) -> fp32 d_out ----------------
__global__ __launch_bounds__(256) void gemm_out64(
    const ushort* __restrict__ C, const ushort* __restrict__ WtU,
    const float* __restrict__ bout, float* __restrict__ out) {
  __shared__ ushort At[2048];
  __shared__ ushort Bs[4096];
  floatx4 acc[4][2];
  int row_base = blockIdx.x * 64, n0 = blockIdx.y * 128;
  tile64_mainloop<false>(C, WtU, row_base, n0, At, Bs, acc);
  const int t = threadIdx.x, lane = t & 63, wv = t >> 6;
  const int quad = lane >> 4, l15 = lane & 15;
#pragma unroll
  for (int tjj = 0; tjj < 2; ++tjj) {
    int gcol = n0 + (2 * wv + tjj) * 16 + l15;
    float b = bout[gcol];
#pragma unroll
    for (int ti = 0; ti < 4; ++ti)
#pragma unroll
      for (int reg = 0; reg < 4; ++reg) {
        int grow = row_base + ti * 16 + quad * 4 + reg;
        out[(size_t)grow * 256 + gcol] = acc[ti][tjj][reg] + b;
      }
  }
}

extern "C" void kernel_launch(void* const* d_in, const int* in_sizes, int n_in,
                              void* d_out, int out_size, void* d_ws, size_t ws_size,
                              hipStream_t stream) {
  const float* query  = (const float*)d_in[0];
  const float* refp   = (const float*)d_in[1];
  const float* inpf   = (const float*)d_in[2];
  const float* W_val  = (const float*)d_in[5];
  const float* b_val  = (const float*)d_in[6];
  const float* W_off  = (const float*)d_in[7];
  const float* b_off  = (const float*)d_in[8];
  const float* W_attn = (const float*)d_in[9];
  const float* b_attn = (const float*)d_in[10];
  const float* W_out  = (const float*)d_in[11];
  const float* b_out  = (const float*)d_in[12];

  char* ws = (char*)d_ws;
  ushort* Wt    = (ushort*)ws;                        // 458,752 B used (1 MB reserved)
  ushort* value = (ushort*)(ws + 1048576);            // 22,282,240 B (bf16)
  uint4*  tbl   = (uint4*)(ws + 23330816);            // 89,128,960 B (16 B slots)
  ushort* coreo = (ushort*)(ws + 112459776);          // 22,282,240 B (bf16)
  // peak = 134,742,016 B

  dim3 blk(256);
  wcast_kernel<<<dim3(256, 4), blk, 0, stream>>>(W_val, W_off, W_attn, W_out, Wt);
  gemm_val64  <<<dim3(680, 2), blk, 0, stream>>>(inpf, Wt, b_val, value);
  gemm_oa_kernel<<<dim3(2720), blk, 0, stream>>>(query, Wt + 65536, b_off, b_attn, refp, tbl);
  core_kernel <<<dim3(21760), dim3(512), 0, stream>>>(value, tbl, (uint*)coreo);
  gemm_out64  <<<dim3(680, 2), blk, 0, stream>>>(coreo, Wt + 163840, b_out, (float*)d_out);
}